// Round 1
// baseline (544.416 us; speedup 1.0000x reference)
//
#include <hip/hip_runtime.h>
#include <hip/hip_bf16.h>
#include <cstdint>
#include <cstddef>

// ---------- types ----------
typedef __bf16 bf16_t;
typedef __bf16 bf16x8 __attribute__((ext_vector_type(8)));
typedef __bf16 bf16x4 __attribute__((ext_vector_type(4)));
typedef float  f32x4  __attribute__((ext_vector_type(4)));

#define DIM    1024
#define NCOEF  8
#define KTOT   (DIM + DIM * NCOEF)   // 9216
#define KHALF  (KTOT / 2)            // 4608 per split-K block
#define NT     144                   // K-tiles (BK=32) per block
#define NKNOT  12
#define BATCH  8192
#define LN_EPS 1e-5f

// ---------- device helpers ----------
__device__ __forceinline__ float gelu_exact(float x) {
    return 0.5f * x * (1.0f + erff(x * 0.70710678118654752440f));
}

__device__ __forceinline__ void gl_lds16(const void* g, void* l) {
    __builtin_amdgcn_global_load_lds(
        (const __attribute__((address_space(1))) unsigned int*)(uintptr_t)g,
        (__attribute__((address_space(3))) unsigned int*)(uintptr_t)l, 16, 0, 0);
}
__device__ __forceinline__ void gl_lds4(const void* g, void* l) {
    __builtin_amdgcn_global_load_lds(
        (const __attribute__((address_space(1))) unsigned int*)(uintptr_t)g,
        (__attribute__((address_space(3))) unsigned int*)(uintptr_t)l, 4, 0, 0);
}

__device__ __forceinline__ uint64_t pack4bf(float a, float b, float c, float d) {
    union { bf16_t h[4]; uint64_t q; } u;
    u.h[0] = (bf16_t)a; u.h[1] = (bf16_t)b; u.h[2] = (bf16_t)c; u.h[3] = (bf16_t)d;
    return u.q;
}

// Uniform cubic B-spline: 8 bf16 bases of one feature as 16 bytes (lo,hi).
__device__ __forceinline__ void spline8(float x, float g0, float invh,
                                        uint64_t& lo, uint64_t& hi) {
    float u = (x - g0) * invh;
    float jf = floorf(u);
    int j = (int)jf;
    float f = u - jf;
    float f2 = f * f, f3 = f2 * f;
    float om = 1.0f - f, om2 = om * om;
    float w0 = om2 * om * (1.0f / 6.0f);
    float w3 = f3 * (1.0f / 6.0f);
    float w1 = fmaf(0.5f, f3, 2.0f / 3.0f) - f2;
    float w2 = 1.0f - w0 - w1 - w3;
    uint64_t W64 = pack4bf(w0, w1, w2, w3);
    if (!(u >= 0.0f && u < 11.0f)) W64 = 0;
    int sh = (j - 3) * 16;
    if (sh >= 0) {
        int s = sh & 63;
        uint64_t loW = W64 << s;
        uint64_t hiW = s ? (W64 >> (64 - s)) : 0ull;
        lo = (sh < 64) ? loW : 0ull;
        hi = (sh < 64) ? hiW : loW;
    } else {
        lo = W64 >> (-sh);
        hi = 0ull;
    }
}

// ---------- W pack: [base_w | spline_w] f32 -> bf16, K-packed ----------
__global__ void pack_w(const float* __restrict__ bw, const float* __restrict__ sw,
                       bf16_t* __restrict__ W) {
    int idx = blockIdx.x * 256 + threadIdx.x;      // (layer,o,j)
    bf16_t* wrow = W + (size_t)(idx >> 10) * KTOT;
    int j = idx & 1023;
    wrow[j] = (bf16_t)bw[idx];
    const float4* sp = (const float4*)(sw + (size_t)idx * NCOEF);
    float4 s0 = sp[0], s1 = sp[1];
    bf16x8 v;
    v[0] = (bf16_t)s0.x; v[1] = (bf16_t)s0.y; v[2] = (bf16_t)s0.z; v[3] = (bf16_t)s0.w;
    v[4] = (bf16_t)s1.x; v[5] = (bf16_t)s1.y; v[6] = (bf16_t)s1.z; v[7] = (bf16_t)s1.w;
    *(bf16x8*)(wrow + DIM + j * NCOEF) = v;
}

// ---------- gelu precompute ----------
__global__ void prep_gelu(const float* __restrict__ x, bf16_t* __restrict__ g) {
    int idx = blockIdx.x * 256 + threadIdx.x;
    float4 v = ((const float4*)x)[idx];
    bf16x4 o;
    o[0] = (bf16_t)gelu_exact(v.x); o[1] = (bf16_t)gelu_exact(v.y);
    o[2] = (bf16_t)gelu_exact(v.z); o[3] = (bf16_t)gelu_exact(v.w);
    *(bf16x4*)(g + (size_t)idx * 4) = o;
}

// =====================================================================
// Fused GEMM v2: BM=256, BN=256, BK=32, split-K=2, 8 waves.
// 4-slot LDS rotation (slot = tile&3), tiles prefetched 2 ahead,
// counted s_waitcnt vmcnt(6) at tile boundaries (never drain to 0),
// chunk-XOR LDS swizzle, setprio around MFMA clusters.
// Per iter (2 K-tiles): p0[stage B(2t+2); vmcnt(6); bar; read B+A(lo); 16 MFMA; bar]
//                       p1[stage Y(2t+4); stage/compute A(2t+2); read A(hi); 16 MFMA]
//                       p2/p3 same for odd tile; lgkmcnt(0) before iter-end bar.
// =====================================================================

#define STAGE_B(U, S) \
    gl_lds16(BgA + (size_t)(U) * 32, ldsb + 32768 + (S) * 8192 + tid * 8); \
    gl_lds16(BgB + (size_t)(U) * 32, ldsb + 32768 + (S) * 8192 + 4096 + tid * 8);

#define STAGE_G(U, S) \
    gl_lds16(GgA + (size_t)(U) * 32, ldsb + (S) * 8192 + tid * 8); \
    gl_lds16(GgB + (size_t)(U) * 32, ldsb + (S) * 8192 + 4096 + tid * 8);

#define STAGE_Y(U, S) { int jb_ = jb0 + (U) * 4; \
    gl_lds4(YgA + jb_, ldsy + (S) * 1024 + tid); \
    gl_lds4(YgB + jb_, ldsy + (S) * 1024 + 512 + tid); }

#define COMPUTE_A(S) { \
    float x1_ = ldsy[(S) * 1024 + tid], x2_ = ldsy[(S) * 1024 + 512 + tid]; \
    uint64_t lo_, hi_; union { uint64_t u[2]; uint4 v; } ov_; \
    spline8(x1_, g0, invh, lo_, hi_); ov_.u[0] = lo_; ov_.u[1] = hi_; \
    *(uint4*)(ldsb + (S) * 8192 + tid * 8) = ov_.v; \
    spline8(x2_, g0, invh, lo_, hi_); ov_.u[0] = lo_; ov_.u[1] = hi_; \
    *(uint4*)(ldsb + (S) * 8192 + 4096 + tid * 8) = ov_.v; }

#define RD_B(S) { const bf16_t* Bb_ = ldsb + 32768 + (S) * 8192 + bOff; \
    b0 = *(const bf16x8*)(Bb_);        b1 = *(const bf16x8*)(Bb_ + 512); \
    b2 = *(const bf16x8*)(Bb_ + 1024); b3 = *(const bf16x8*)(Bb_ + 1536); }

#define MF_ROW(I, A_) \
    acc[I][0] = __builtin_amdgcn_mfma_f32_16x16x32_bf16(A_, b0, acc[I][0], 0, 0, 0); \
    acc[I][1] = __builtin_amdgcn_mfma_f32_16x16x32_bf16(A_, b1, acc[I][1], 0, 0, 0); \
    acc[I][2] = __builtin_amdgcn_mfma_f32_16x16x32_bf16(A_, b2, acc[I][2], 0, 0, 0); \
    acc[I][3] = __builtin_amdgcn_mfma_f32_16x16x32_bf16(A_, b3, acc[I][3], 0, 0, 0);

#define MF_HALF(S, IB) { const bf16_t* Ab_ = ldsb + (S) * 8192 + aOff + (IB) * 2048; \
    bf16x8 a0_ = *(const bf16x8*)(Ab_),        a1_ = *(const bf16x8*)(Ab_ + 512), \
           a2_ = *(const bf16x8*)(Ab_ + 1024), a3_ = *(const bf16x8*)(Ab_ + 1536); \
    __builtin_amdgcn_s_setprio(1); \
    MF_ROW((IB) * 4 + 0, a0_) MF_ROW((IB) * 4 + 1, a1_) \
    MF_ROW((IB) * 4 + 2, a2_) MF_ROW((IB) * 4 + 3, a3_) \
    __builtin_amdgcn_s_setprio(0); }

#define ITER(T, SA0, SA1, SS0, SS1) { \
    const int u2_ = 2 * (T) + 2, u3_ = 2 * (T) + 3; \
    bf16x8 b0, b1, b2, b3; \
    /* ---- p0 ---- */ \
    if (u2_ < NT) { STAGE_B(u2_, SS0) } \
    if ((T) < 70) { asm volatile("s_waitcnt vmcnt(6)" ::: "memory"); } \
    else          { asm volatile("s_waitcnt vmcnt(0)" ::: "memory"); } \
    __builtin_amdgcn_s_barrier(); \
    asm volatile("" ::: "memory"); \
    RD_B(SA0) \
    MF_HALF(SA0, 0) \
    __builtin_amdgcn_s_barrier(); \
    /* ---- p1 ---- */ \
    if (u2_ + 2 < NT && (koff0 + (u2_ + 2) * 32) >= DIM) { STAGE_Y(u2_ + 2, SA0) } \
    if (u2_ < NT) { \
        if (koff0 + u2_ * 32 < DIM) { STAGE_G(u2_, SS0) } \
        else                        { COMPUTE_A(SS0) } \
    } \
    MF_HALF(SA0, 1) \
    /* ---- p2 ---- */ \
    if (u3_ < NT) { STAGE_B(u3_, SS1) } \
    if ((T) < 70) { asm volatile("s_waitcnt vmcnt(6)" ::: "memory"); } \
    else          { asm volatile("s_waitcnt vmcnt(0)" ::: "memory"); } \
    __builtin_amdgcn_s_barrier(); \
    asm volatile("" ::: "memory"); \
    RD_B(SA1) \
    MF_HALF(SA1, 0) \
    __builtin_amdgcn_s_barrier(); \
    /* ---- p3 ---- */ \
    if (u3_ + 2 < NT && (koff0 + (u3_ + 2) * 32) >= DIM) { STAGE_Y(u3_ + 2, SA1) } \
    if (u3_ < NT) { \
        if (koff0 + u3_ * 32 < DIM) { STAGE_G(u3_, SS1) } \
        else                        { COMPUTE_A(SS1) } \
    } \
    MF_HALF(SA1, 1) \
    asm volatile("s_waitcnt lgkmcnt(0)" ::: "memory"); \
    __builtin_amdgcn_s_barrier(); \
}

__global__ __launch_bounds__(512, 2) void gemm_fused(
    const float* __restrict__ Y,       // [R,1024] f32 raw layer input
    const bf16_t* __restrict__ G,      // [R,1024] bf16 gelu(Y)
    const bf16_t* __restrict__ W,      // [1024,9216] packed bf16
    float* __restrict__ C,             // [2, R, 1024] f32 split-K partials
    const float* __restrict__ gp,      // knot row
    int mmask, int mshift, int rows) {
    __shared__ __align__(16) unsigned char smem[147456];   // 128K AB + 16K Y
    bf16_t* __restrict__ ldsb = (bf16_t*)smem;
    float*  __restrict__ ldsy = (float*)(smem + 131072);

    const int tid = threadIdx.x;
    const int l = tid & 63, wv = tid >> 6;
    const int wm = wv >> 2, wn = wv & 3;        // 2M x 4N waves, 128x64 each

    // XCD swizzle: each XCD owns one (bn,ks) pair -> B panel is L2-resident
    const int chunk = mmask + 1;
    const int bid = blockIdx.x;
    const int wg = (bid & 7) * chunk + (bid >> 3);
    const int bm = wg & mmask;
    const int bn = (wg >> mshift) & 3;
    const int ks = wg >> (mshift + 2);
    const int row0 = bm << 8;
    const int col0 = bn << 8;
    const int koff0 = ks * KHALF;
    const int jb0 = (koff0 >> 3) - 128;         // spline feature base - per-tile*4

    const float g0 = gp[0];
    const float invh = 1.0f / (gp[1] - gp[0]);

    // ---- staging geometry (thread covers rows srow, srow+128 of each tile) ----
    const int srow = tid >> 2;                  // 0..127
    const int slc  = (tid & 3) ^ ((srow >> 1) & 3);   // logical chunk (swizzled src)
    const bf16_t* __restrict__ BgA = W + (size_t)(col0 + srow) * KTOT + koff0 + slc * 8;
    const bf16_t* __restrict__ BgB = BgA + (size_t)128 * KTOT;
    const bf16_t* __restrict__ GgA = G + (size_t)(row0 + srow) * DIM + slc * 8;
    const bf16_t* __restrict__ GgB = GgA + (size_t)128 * DIM;
    const float*  __restrict__ YgA = Y + (size_t)(row0 + srow) * DIM + slc;
    const float*  __restrict__ YgB = YgA + (size_t)128 * DIM;

    // ---- fragment-read offsets (elements); phys chunk = logical ^ ((row>>1)&3) ----
    const int l15 = l & 15;
    const int pc = (l >> 4) ^ ((l15 >> 1) & 3);
    const int aOff = (wm * 128 + l15) * 32 + pc * 8;            // + slot*8192 + i*512
    const int bOff = (wn * 64 + l15) * 32 + pc * 8;             // + 32768 + slot*8192 + j*512

    f32x4 acc[8][4] = {};

    // ---- prologue: tiles 0,1 fully resident, Y(0..3) if spline ----
    STAGE_B(0, 0)
    STAGE_B(1, 1)
    if (koff0 == 0) {                           // ks=0: tiles 0,1 are gelu region
        STAGE_G(0, 0)
        STAGE_G(1, 1)
        asm volatile("s_waitcnt vmcnt(0)" ::: "memory");
        __builtin_amdgcn_s_barrier();
        asm volatile("" ::: "memory");
    } else {                                    // ks=1: all spline
        STAGE_Y(0, 0) STAGE_Y(1, 1) STAGE_Y(2, 2) STAGE_Y(3, 3)
        asm volatile("s_waitcnt vmcnt(0)" ::: "memory");
        __builtin_amdgcn_s_barrier();
        asm volatile("" ::: "memory");
        COMPUTE_A(0)
        COMPUTE_A(1)
        asm volatile("s_waitcnt lgkmcnt(0)" ::: "memory");
        __builtin_amdgcn_s_barrier();
        asm volatile("" ::: "memory");
    }

    // ---- main loop: 72 iters, 2 K-tiles each, slot parity static via unroll-by-2 ----
#pragma unroll 1
    for (int t = 0; t < 72; t += 2) {
        ITER(t,     0, 1, 2, 3)
        ITER(t + 1, 2, 3, 0, 1)
    }

    // ---- epilogue: write split-K partial ----
    float* __restrict__ Cp = C + (size_t)ks * rows * DIM;
    const int r0 = row0 + wm * 128 + (l >> 4) * 4;
    const int c0 = col0 + wn * 64 + l15;
#pragma unroll
    for (int i = 0; i < 8; i++)
#pragma unroll
        for (int j = 0; j < 4; j++)
#pragma unroll
            for (int r = 0; r < 4; r++)
                Cp[(size_t)(r0 + i * 16 + r) * DIM + c0 + j * 16] = acc[i][j][r];
}

// ---------- LayerNorm + PReLU (sums split-K partials) -> y (f32) + gelu(y) (bf16) ----------
__global__ void ln_mid(const float* __restrict__ ha, const float* __restrict__ hb,
                       const float* __restrict__ g_ln, const float* __restrict__ b_ln,
                       const float* __restrict__ pa,
                       float* __restrict__ y, bf16_t* __restrict__ yg) {
    const int row = blockIdx.x, tid = threadIdx.x;
    const int w = tid >> 6, l = tid & 63;
    f32x4 va = *(const f32x4*)(ha + (size_t)row * DIM + tid * 4);
    f32x4 vb = *(const f32x4*)(hb + (size_t)row * DIM + tid * 4);
    f32x4 v = va + vb;
    float s = v[0] + v[1] + v[2] + v[3];
    float q = v[0] * v[0] + v[1] * v[1] + v[2] * v[2] + v[3] * v[3];
#pragma unroll
    for (int o = 32; o > 0; o >>= 1) { s += __shfl_xor(s, o); q += __shfl_xor(q, o); }
    __shared__ float rs[4], rq[4];
    if (l == 0) { rs[w] = s; rq[w] = q; }
    __syncthreads();
    s = rs[0] + rs[1] + rs[2] + rs[3];
    q = rq[0] + rq[1] + rq[2] + rq[3];
    float mean = s * (1.0f / DIM);
    float var = q * (1.0f / DIM) - mean * mean;
    float rstd = rsqrtf(var + LN_EPS);
    float a = pa[0];
    f32x4 o4;
    bf16x4 g4;
#pragma unroll
    for (int c = 0; c < 4; c++) {
        int col = tid * 4 + c;
        float yv = (v[c] - mean) * rstd * g_ln[col] + b_ln[col];
        yv = (yv >= 0.0f) ? yv : a * yv;
        o4[c] = yv;
        g4[c] = (bf16_t)gelu_exact(yv);
    }
    *(f32x4*)(y + (size_t)row * DIM + tid * 4) = o4;
    *(bf16x4*)(yg + (size_t)row * DIM + tid * 4) = g4;
}

// ---------- final LayerNorm + PReLU (sums split-K partials) -> f32 out ----------
__global__ void ln_out(const float* __restrict__ ha, const float* __restrict__ hb,
                       const float* __restrict__ g_ln, const float* __restrict__ b_ln,
                       const float* __restrict__ pa, float* __restrict__ out) {
    const int row = blockIdx.x, tid = threadIdx.x;
    const int w = tid >> 6, l = tid & 63;
    f32x4 va = *(const f32x4*)(ha + (size_t)row * DIM + tid * 4);
    f32x4 vb = *(const f32x4*)(hb + (size_t)row * DIM + tid * 4);
    f32x4 v = va + vb;
    float s = v[0] + v[1] + v[2] + v[3];
    float q = v[0] * v[0] + v[1] * v[1] + v[2] * v[2] + v[3] * v[3];
#pragma unroll
    for (int o = 32; o > 0; o >>= 1) { s += __shfl_xor(s, o); q += __shfl_xor(q, o); }
    __shared__ float rs[4], rq[4];
    if (l == 0) { rs[w] = s; rq[w] = q; }
    __syncthreads();
    s = rs[0] + rs[1] + rs[2] + rs[3];
    q = rq[0] + rq[1] + rq[2] + rq[3];
    float mean = s * (1.0f / DIM);
    float var = q * (1.0f / DIM) - mean * mean;
    float rstd = rsqrtf(var + LN_EPS);
    float a = pa[0];
    f32x4 o4;
#pragma unroll
    for (int c = 0; c < 4; c++) {
        int col = tid * 4 + c;
        float yv = (v[c] - mean) * rstd * g_ln[col] + b_ln[col];
        o4[c] = (yv >= 0.0f) ? yv : a * yv;
    }
    *(f32x4*)(out + (size_t)row * DIM + tid * 4) = o4;
}

// ---------- launch ----------
extern "C" void kernel_launch(void* const* d_in, const int* in_sizes, int n_in,
                              void* d_out, int out_size, void* d_ws, size_t ws_size,
                              hipStream_t stream) {
    const float* x    = (const float*)d_in[0];
    const float* bw   = (const float*)d_in[1];
    const float* sw   = (const float*)d_in[2];
    const float* ln_g = (const float*)d_in[3];
    const float* ln_b = (const float*)d_in[4];
    const float* pa   = (const float*)d_in[5];
    const float* gridK = (const float*)d_in[6];
    float* out = (float*)d_out;

    const size_t wbytes = (size_t)2 * DIM * KTOT * sizeof(bf16_t);   // 37.75 MB
    // need: ygel R*D*2 + ybuf R*D*4 + hbuf 2*R*D*4 = R*D*14 bytes
    int R = 8192;
    while (R > 256 && wbytes + (size_t)R * DIM * 14 > ws_size) R >>= 1;
    int mtiles = R / 256;                // BM = 256
    int mshift = 0; while ((1 << mshift) < mtiles) mshift++;
    int mmask = mtiles - 1;
    int grid = mtiles * 8;               // 4 bn x 2 ks

    char* wsc = (char*)d_ws;
    bf16_t* Wbuf = (bf16_t*)wsc;
    bf16_t* ygel = (bf16_t*)(wsc + wbytes);
    float*  ybuf = (float*)(wsc + wbytes + (size_t)R * DIM * 2);
    float*  hbuf = (float*)(wsc + wbytes + (size_t)R * DIM * 6);   // 2 partials

    pack_w<<<(2 * DIM * DIM) / 256, 256, 0, stream>>>(bw, sw, Wbuf);

    const int nslab = BATCH / R;
    for (int sidx = 0; sidx < nslab; sidx++) {
        const size_t row0 = (size_t)sidx * R;
        const float* x0 = x + row0 * DIM;
        // layer 0
        prep_gelu<<<R * DIM / 1024, 256, 0, stream>>>(x0, ygel);
        gemm_fused<<<grid, 512, 0, stream>>>(x0, ygel, Wbuf, hbuf,
                                             gridK, mmask, mshift, R);
        ln_mid<<<R, 256, 0, stream>>>(hbuf, hbuf + (size_t)R * DIM,
                                      ln_g, ln_b, pa, ybuf, ygel);
        // layer 1
        gemm_fused<<<grid, 512, 0, stream>>>(ybuf, ygel, Wbuf + (size_t)DIM * KTOT, hbuf,
                                             gridK + DIM * NKNOT, mmask, mshift, R);
        ln_out<<<R, 256, 0, stream>>>(hbuf, hbuf + (size_t)R * DIM,
                                      ln_g + DIM, ln_b + DIM, pa + 1, out + row0 * DIM);
    }
}